// Round 5
// baseline (228.917 us; speedup 1.0000x reference)
//
#include <hip/hip_runtime.h>

// Sparsemax over rows: B=131072, D=256, fp32.
// PERSISTENT grid-stride waves, 2 rows (1 pair) per wave per step, with
// software-pipelined prefetch of the next pair: R1-R4 showed time pinned at
// ~80us regardless of reduction style -- waves were short-lived and died
// stalled on their first load (avg wave lifetime ~15k cycles, HBM 2.5 TB/s).
// The harness's own fill kernels hit 6.7 TB/s at 9.5% occupancy via exactly
// this persistent+pipelined structure.
// tau via Michelot from A0={z > max-1} (tau* in [max-1,max) => superset),
// DPP reductions on the VALU pipe, rcp instead of IEEE divide.

#define D_COLS 256
#define NBLOCKS 1024  // 4 blocks/CU, 16 waves/CU; 16 row-pairs per wave

#if defined(__has_builtin) && __has_builtin(__builtin_amdgcn_rcpf)
#define FAST_RCP(x) __builtin_amdgcn_rcpf(x)
#else
#define FAST_RCP(x) (1.0f / (x))
#endif

// DPP move with 0-identity (bound_ctrl: invalid lanes read 0).
#define DPP_MOV0(v, ctrl) \
  __int_as_float(__builtin_amdgcn_update_dpp(0, __float_as_int(v), (ctrl), 0xF, 0xF, true))

// Full-wave sum; valid in lane 63. ctrl: row_shr:1/2/4/8, bcast15, bcast31.
__device__ __forceinline__ float wave_sum_l63(float v) {
  v += DPP_MOV0(v, 0x111);
  v += DPP_MOV0(v, 0x112);
  v += DPP_MOV0(v, 0x114);
  v += DPP_MOV0(v, 0x118);
  v += DPP_MOV0(v, 0x142);
  v += DPP_MOV0(v, 0x143);
  return v;
}

// Full-wave max of POSITIVE values (0-identity safe); valid in lane 63.
__device__ __forceinline__ float wave_maxpos_l63(float v) {
  v = fmaxf(v, DPP_MOV0(v, 0x111));
  v = fmaxf(v, DPP_MOV0(v, 0x112));
  v = fmaxf(v, DPP_MOV0(v, 0x114));
  v = fmaxf(v, DPP_MOV0(v, 0x118));
  v = fmaxf(v, DPP_MOV0(v, 0x142));
  v = fmaxf(v, DPP_MOV0(v, 0x143));
  return v;
}

__device__ __forceinline__ float rd63(float v) {
  return __int_as_float(__builtin_amdgcn_readlane(__float_as_int(v), 63));
}

__global__ __launch_bounds__(256) void sparsemax_kernel(
    const float* __restrict__ x, float* __restrict__ out, int npairs) {
  const int lane = threadIdx.x & 63;
  int p = (int)((blockIdx.x * blockDim.x + threadIdx.x) >> 6);  // global wave id
  const int stride = (int)((gridDim.x * blockDim.x) >> 6);      // total waves
  if (p >= npairs) return;

  const float4* __restrict__ xi = (const float4*)x;
  float4* __restrict__ xo = (float4*)out;

  // Prologue: load first pair. Row r = 64 float4s; lane owns element r*64+lane.
  float4 a0 = xi[(size_t)(2 * p) * 64 + lane];
  float4 a1 = xi[(size_t)(2 * p + 1) * 64 + lane];

  for (;;) {
    const int pn = p + stride;
    const bool more = pn < npairs;

    // Prefetch next pair BEFORE computing current one (hides VMEM latency).
    float4 b0, b1;
    if (more) {
      b0 = xi[(size_t)(2 * pn) * 64 + lane];
      b1 = xi[(size_t)(2 * pn + 1) * 64 + lane];
    }

    // ---- tau for the current pair (a0, a1) ----
    // Biased max (+1024 => positive, so 0-identity DPP max is valid);
    // un-bias is Sterbenz-exact, initial rounding <=2^-13 << 2e-2 threshold.
    float bm0 = fmaxf(fmaxf(a0.x, a0.y), fmaxf(a0.z, a0.w)) + 1024.0f;
    float bm1 = fmaxf(fmaxf(a1.x, a1.y), fmaxf(a1.z, a1.w)) + 1024.0f;
    bm0 = wave_maxpos_l63(bm0);
    bm1 = wave_maxpos_l63(bm1);
    float tau0 = rd63(bm0) - 1025.0f;  // = max - 1
    float tau1 = rd63(bm1) - 1025.0f;
    int p0 = -1, p1 = -1;

    for (int it = 0; it < 64; ++it) {
      int c0 = __popcll(__ballot(a0.x > tau0)) + __popcll(__ballot(a0.y > tau0)) +
               __popcll(__ballot(a0.z > tau0)) + __popcll(__ballot(a0.w > tau0));
      int c1 = __popcll(__ballot(a1.x > tau1)) + __popcll(__ballot(a1.y > tau1)) +
               __popcll(__ballot(a1.z > tau1)) + __popcll(__ballot(a1.w > tau1));

      if (c0 == p0 && c1 == p1) break;  // both active sets stable => done

      float s0 = ((a0.x > tau0) ? a0.x : 0.0f) + ((a0.y > tau0) ? a0.y : 0.0f) +
                 ((a0.z > tau0) ? a0.z : 0.0f) + ((a0.w > tau0) ? a0.w : 0.0f);
      float s1 = ((a1.x > tau1) ? a1.x : 0.0f) + ((a1.y > tau1) ? a1.y : 0.0f) +
                 ((a1.z > tau1) ? a1.z : 0.0f) + ((a1.w > tau1) ? a1.w : 0.0f);
      s0 = wave_sum_l63(s0);
      s1 = wave_sum_l63(s1);

      tau0 = (rd63(s0) - 1.0f) * FAST_RCP((float)c0);  // idempotent if stable
      tau1 = (rd63(s1) - 1.0f) * FAST_RCP((float)c1);
      p0 = c0;
      p1 = c1;
    }

    float4 o0, o1;
    o0.x = fmaxf(a0.x - tau0, 0.0f); o0.y = fmaxf(a0.y - tau0, 0.0f);
    o0.z = fmaxf(a0.z - tau0, 0.0f); o0.w = fmaxf(a0.w - tau0, 0.0f);
    o1.x = fmaxf(a1.x - tau1, 0.0f); o1.y = fmaxf(a1.y - tau1, 0.0f);
    o1.z = fmaxf(a1.z - tau1, 0.0f); o1.w = fmaxf(a1.w - tau1, 0.0f);
    xo[(size_t)(2 * p) * 64 + lane] = o0;
    xo[(size_t)(2 * p + 1) * 64 + lane] = o1;

    if (!more) break;
    a0 = b0;  // retire prefetch into current
    a1 = b1;
    p = pn;
  }
}

extern "C" void kernel_launch(void* const* d_in, const int* in_sizes, int n_in,
                              void* d_out, int out_size, void* d_ws, size_t ws_size,
                              hipStream_t stream) {
  const float* x = (const float*)d_in[0];
  float* out = (float*)d_out;
  const int nrows = in_sizes[0] / D_COLS;
  const int npairs = nrows / 2;  // B=131072 is even
  sparsemax_kernel<<<NBLOCKS, 256, 0, stream>>>(x, out, npairs);
}